// Round 1
// baseline (448.043 us; speedup 1.0000x reference)
//
#include <hip/hip_runtime.h>
#include <stdint.h>

// ---------------------------------------------------------------------------
// 2D DCT-II (unnormalized) of a 4096x4096 fp32 matrix via two bf16 MFMA GEMMs:
//   D[k][m] = cos(pi*k*(2m+1)/8192)        (same matrix for rows & cols, M=N)
//   C1 = D * X^T        (bt-GEMM: A=D, Bt=X)      -> C1 = Y^T   (bf16)
//   Z  = D * C1^T       (bt-GEMM: A=D, Bt=C1)     -> d_out      (fp32)
// Both GEMMs identical structure: 128x128 tile, BK=64, 16x16x32 bf16 MFMA,
// global_load_lds width=16 staging with XOR chunk swizzle on the global side.
// ---------------------------------------------------------------------------

#define BM 128
#define BKK 64
#define KDIM 4096

typedef __attribute__((ext_vector_type(8))) short bf16x8;   // 8 bf16 = 4 VGPRs
typedef __attribute__((ext_vector_type(4))) float f32x4;

__device__ __forceinline__ unsigned short f2bf(float f) {
    union { float f; uint32_t u; } v; v.f = f;
    return (unsigned short)((v.u + 0x7FFFu + ((v.u >> 16) & 1u)) >> 16);
}

// D[k][m] = cos(pi*k*(2m+1)/8192), exact integer reduction mod 16384 so the
// cos argument stays in [0, 2*pi) (cosf arg-reduction error is irrelevant).
__global__ void gen_dct(unsigned short* __restrict__ D) {
    uint32_t idx = blockIdx.x * 256 + threadIdx.x;
    uint32_t k = idx >> 12;
    uint32_t m = idx & 4095u;
    uint32_t r = (k * (2u * m + 1u)) & 16383u;
    float ang = (float)r * 3.8349519697141029e-4f;   // pi/8192
    D[idx] = f2bf(__cosf(ang));
}

__global__ void cvt_bf16(const float4* __restrict__ X, ushort4* __restrict__ Xb) {
    uint32_t idx = blockIdx.x * 256 + threadIdx.x;
    float4 v = X[idx];
    ushort4 o;
    o.x = f2bf(v.x); o.y = f2bf(v.y); o.z = f2bf(v.z); o.w = f2bf(v.w);
    Xb[idx] = o;
}

// C[m][n] = sum_k A[m][k] * Bt[n][k], all 4096x4096 row-major.
template <bool OUT_BF16>
__global__ __launch_bounds__(256)
void gemm_bt(const unsigned short* __restrict__ A,
             const unsigned short* __restrict__ Bt,
             void* __restrict__ Cout)
{
    __shared__ __align__(16) unsigned short As[BM * BKK];   // 16 KB
    __shared__ __align__(16) unsigned short Bs[BM * BKK];   // 16 KB

    const int tid  = threadIdx.x;
    const int lane = tid & 63;
    const int wave = tid >> 6;
    const int l15  = lane & 15;
    const int quad = lane >> 4;
    const int wm   = (wave & 1) * 64;    // wave's 64x64 sub-tile
    const int wn   = (wave >> 1) * 64;
    const int bm   = blockIdx.y;
    const int bn   = blockIdx.x;

    f32x4 acc[4][4] = {};   // zero-init accumulators

    for (int k0 = 0; k0 < KDIM; k0 += BKK) {
        // ---- stage A,B tiles: 128 rows x 64 bf16 each, 16B per lane.
        // chunk ch = i*256+tid; LDS dest = base + lane*16 (contiguous order,
        // required by global_load_lds). Swizzle: stored chunk s holds actual
        // chunk c = s ^ (row&7) -- permutation applied on the GLOBAL address,
        // so staging stays coalesced (same 128B per 8-lane row, reordered).
        #pragma unroll
        for (int i = 0; i < 4; ++i) {
            int ch  = i * 256 + tid;        // 0..1023
            int row = ch >> 3;              // 0..127
            int s   = ch & 7;
            int c   = s ^ (row & 7);
            const unsigned short* gA = A  + (size_t)(bm * BM + row) * KDIM + k0 + c * 8;
            const unsigned short* gB = Bt + (size_t)(bn * BM + row) * KDIM + k0 + c * 8;
            __builtin_amdgcn_global_load_lds(
                (const __attribute__((address_space(1))) void*)gA,
                (__attribute__((address_space(3))) void*)(&As[ch * 8]), 16, 0, 0);
            __builtin_amdgcn_global_load_lds(
                (const __attribute__((address_space(1))) void*)gB,
                (__attribute__((address_space(3))) void*)(&Bs[ch * 8]), 16, 0, 0);
        }
        __syncthreads();

        // ---- 2 k-steps of 16x16x32, 4x4 tiles per wave = 32 MFMA / iter
        #pragma unroll
        for (int ks = 0; ks < 2; ++ks) {
            bf16x8 af[4], bfr[4];
            #pragma unroll
            for (int i = 0; i < 4; ++i) {
                int m = wm + i * 16 + l15;          // A row
                int c = ks * 4 + quad;              // actual k-chunk
                int s = c ^ (m & 7);                // stored chunk
                af[i] = *(const bf16x8*)&As[m * BKK + s * 8];
            }
            #pragma unroll
            for (int j = 0; j < 4; ++j) {
                int n = wn + j * 16 + l15;          // Bt row
                int c = ks * 4 + quad;
                int s = c ^ (n & 7);
                bfr[j] = *(const bf16x8*)&Bs[n * BKK + s * 8];
            }
            #pragma unroll
            for (int i = 0; i < 4; ++i)
                #pragma unroll
                for (int j = 0; j < 4; ++j)
                    acc[i][j] = __builtin_amdgcn_mfma_f32_16x16x32_bf16(
                        af[i], bfr[j], acc[i][j], 0, 0, 0);
        }
        __syncthreads();
    }

    // ---- epilogue: C/D layout col = lane&15, row = quad*4 + reg (m89/m91)
    #pragma unroll
    for (int i = 0; i < 4; ++i) {
        #pragma unroll
        for (int j = 0; j < 4; ++j) {
            int row0 = bm * BM + wm + i * 16 + quad * 4;
            int col  = bn * BM + wn + j * 16 + l15;
            #pragma unroll
            for (int r = 0; r < 4; ++r) {
                float v = acc[i][j][r];
                if (OUT_BF16)
                    ((unsigned short*)Cout)[(size_t)(row0 + r) * KDIM + col] = f2bf(v);
                else
                    ((float*)Cout)[(size_t)(row0 + r) * KDIM + col] = v;
            }
        }
    }
}

extern "C" void kernel_launch(void* const* d_in, const int* in_sizes, int n_in,
                              void* d_out, int out_size, void* d_ws, size_t ws_size,
                              hipStream_t stream) {
    const float* x = (const float*)d_in[0];
    float* out = (float*)d_out;

    const size_t elems = (size_t)KDIM * KDIM;          // 16.7M
    unsigned short* D  = (unsigned short*)d_ws;        // 32 MB
    unsigned short* Xb = D + elems;                    // 32 MB
    unsigned short* C1 = Xb + elems;                   // 32 MB
    if (ws_size < 3 * elems * sizeof(unsigned short)) return;  // fail visibly

    gen_dct<<<elems / 256, 256, 0, stream>>>(D);
    cvt_bf16<<<elems / 4 / 256, 256, 0, stream>>>((const float4*)x, (ushort4*)Xb);

    dim3 grid(KDIM / BM, KDIM / BM);   // 32x32
    gemm_bt<true ><<<grid, 256, 0, stream>>>(D, Xb, (void*)C1);   // C1 = Y^T (bf16)
    gemm_bt<false><<<grid, 256, 0, stream>>>(D, C1, (void*)out);  // Z (fp32)
}

// Round 2
// 260.632 us; speedup vs baseline: 1.7191x; 1.7191x over previous
//
#include <hip/hip_runtime.h>
#include <stdint.h>

// ---------------------------------------------------------------------------
// 2D DCT-II (unnormalized, 4096x4096 fp32) via the reference's own FFT path:
//   per row: v = makhoul_perm(x); V = FFT_4096(v); y[k] = Re(V[k]*expk[k])
// FFT_4096 = 4 radix-8 Stockham (autosort) stages, entirely in LDS (64 KB
// ping-pong, fp32 complex). Pipeline:
//   setup(tables) -> dct_rows(X->B1) -> transpose(B1 in-place)
//                 -> dct_rows(B1 in-place) -> transpose(B1 -> out)
// LDS XOR swizzle phys(e)=e^((e>>3)&7) (a per-64-block permutation) keeps
// stage reads conflict-free and caps write conflicts at ~2-way.
// ---------------------------------------------------------------------------

#define NF 4096

__device__ __forceinline__ int physi(int e) { return e ^ ((e >> 3) & 7); }

__device__ __forceinline__ float2 cadd(float2 a, float2 b) {
    float2 r; r.x = a.x + b.x; r.y = a.y + b.y; return r;
}
__device__ __forceinline__ float2 csub(float2 a, float2 b) {
    float2 r; r.x = a.x - b.x; r.y = a.y - b.y; return r;
}
__device__ __forceinline__ float2 cmulc(float2 a, float2 b) {
    float2 r; r.x = a.x * b.x - a.y * b.y; r.y = a.x * b.y + a.y * b.x; return r;
}
__device__ __forceinline__ float2 rotm(float2 a) {  // -i * a
    float2 r; r.x = a.y; r.y = -a.x; return r;
}

// tw: stages t=1..3, w[p][u] = exp(-2*pi*i*p*u/(8*Ls)), Ls=8,64,512.
//   float2 index: t=1 at 0 (64), t=2 at 64 (512), t=3 at 576 (4096). 4672 total.
// ek: expk[k] = (cos(pi*k/8192), sin(pi*k/8192)), 4096 entries.
__global__ __launch_bounds__(256) void setup_tables(float* __restrict__ tw,
                                                    float* __restrict__ ek) {
    int idx = blockIdx.x * 256 + threadIdx.x;
    if (idx < 4672) {
        int Ls, rel;
        if (idx < 64)       { Ls = 8;   rel = idx; }
        else if (idx < 576) { Ls = 64;  rel = idx - 64; }
        else                { Ls = 512; rel = idx - 576; }
        int p = rel >> 3, u = rel & 7;
        float phi = (float)(p * u) * (6.283185307179586f / (8.0f * (float)Ls));
        float s, c; __sincosf(phi, &s, &c);
        tw[2 * idx]     = c;
        tw[2 * idx + 1] = -s;
    } else if (idx < 8768) {
        int k = idx - 4672;
        float th = (float)k * (3.14159265358979e-1f / 2667.9114f);  // placeholder? no:
        th = (float)k * (3.141592653589793f / 8192.0f);
        float s, c; __sincosf(th, &s, &c);
        ek[2 * k]     = c;
        ek[2 * k + 1] = s;
    }
}

// One workgroup = one row. DCT-II along the row. In may equal Out (all reads
// of the row happen before any write).
__global__ __launch_bounds__(256) void dct_rows(const float* __restrict__ In,
                                                float* __restrict__ Out,
                                                const float* __restrict__ tw,
                                                const float* __restrict__ ek) {
    __shared__ float2 bufA[NF];   // 32 KB
    __shared__ float2 bufB[NF];   // 32 KB  (total exactly 64 KB)
    const int tid = threadIdx.x;
    const int row = blockIdx.x;
    const float* inr = In + (size_t)row * NF;
    float* outr = Out + (size_t)row * NF;

    // ---- stage the real row into bufB's storage (as 4096 floats), coalesced
    float* rstage = (float*)bufB;
    #pragma unroll
    for (int i = 0; i < 4; ++i) {
        int e = tid + 256 * i;                    // float4 index, 0..1023
        float4 v = ((const float4*)inr)[e];
        ((float4*)rstage)[e] = v;
    }
    __syncthreads();

    // ---- Makhoul permutation -> bufA (complex, swizzled)
    #pragma unroll
    for (int i = 0; i < 16; ++i) {
        int n = tid + 256 * i;
        int idx = (n < 2048) ? (2 * n) : (8191 - 2 * n);
        float2 v; v.x = rstage[idx]; v.y = 0.0f;
        bufA[physi(n)] = v;
    }
    __syncthreads();

    // ---- 4 Stockham radix-8 stages: src -> dst, natural-order output
    float2* src = bufA;
    float2* dst = bufB;
    #pragma unroll
    for (int t = 0; t < 4; ++t) {
        const int Ls = 1 << (3 * t);
        const int twoff = (t == 1) ? 0 : (t == 2) ? 64 : 576;  // unused at t=0
        #pragma unroll
        for (int jj = 0; jj < 2; ++jj) {
            int j = tid + 256 * jj;               // job 0..511
            int p = j & (Ls - 1);
            int q = j >> (3 * t);
            float2 x0 = src[physi(j)];
            float2 x1 = src[physi(j + 512)];
            float2 x2 = src[physi(j + 1024)];
            float2 x3 = src[physi(j + 1536)];
            float2 x4 = src[physi(j + 2048)];
            float2 x5 = src[physi(j + 2560)];
            float2 x6 = src[physi(j + 3072)];
            float2 x7 = src[physi(j + 3584)];
            if (t > 0) {
                const float2* twp = (const float2*)tw + twoff + p * 8;
                x1 = cmulc(x1, twp[1]);
                x2 = cmulc(x2, twp[2]);
                x3 = cmulc(x3, twp[3]);
                x4 = cmulc(x4, twp[4]);
                x5 = cmulc(x5, twp[5]);
                x6 = cmulc(x6, twp[6]);
                x7 = cmulc(x7, twp[7]);
            }
            // 8-point DFT (DIT: two DFT4s + twiddled combine)
            float2 t0 = cadd(x0, x4), t1 = csub(x0, x4);
            float2 t2 = cadd(x2, x6), t3 = csub(x2, x6);
            float2 E0 = cadd(t0, t2), E2 = csub(t0, t2);
            float2 r3 = rotm(t3);
            float2 E1 = cadd(t1, r3), E3 = csub(t1, r3);
            float2 s0 = cadd(x1, x5), s1 = csub(x1, x5);
            float2 s2 = cadd(x3, x7), s3 = csub(x3, x7);
            float2 O0 = cadd(s0, s2), O2 = csub(s0, s2);
            float2 r7 = rotm(s3);
            float2 O1 = cadd(s1, r7), O3 = csub(s1, r7);
            const float SQ = 0.7071067811865476f;
            float2 g1; g1.x = SQ * (O1.x + O1.y); g1.y = SQ * (O1.y - O1.x);
            float2 g2 = rotm(O2);
            float2 g3; g3.x = SQ * (O3.y - O3.x); g3.y = -SQ * (O3.x + O3.y);
            int wb = p + 8 * Ls * q;
            dst[physi(wb)]           = cadd(E0, O0);
            dst[physi(wb + Ls)]      = cadd(E1, g1);
            dst[physi(wb + 2 * Ls)]  = cadd(E2, g2);
            dst[physi(wb + 3 * Ls)]  = cadd(E3, g3);
            dst[physi(wb + 4 * Ls)]  = csub(E0, O0);
            dst[physi(wb + 5 * Ls)]  = csub(E1, g1);
            dst[physi(wb + 6 * Ls)]  = csub(E2, g2);
            dst[physi(wb + 7 * Ls)]  = csub(E3, g3);
        }
        __syncthreads();
        float2* tswap = src; src = dst; dst = tswap;
    }
    // result now in src (== bufA after 4 swaps)

    // ---- epilogue: y[k] = Vr*cos + Vi*sin, coalesced float4 stores
    #pragma unroll
    for (int i = 0; i < 4; ++i) {
        int kb = tid + 256 * i;                   // float4 index
        float4 w;
        float* wp = (float*)&w;
        #pragma unroll
        for (int c = 0; c < 4; ++c) {
            int k = 4 * kb + c;
            float2 V = src[physi(k)];
            float2 E = ((const float2*)ek)[k];
            wp[c] = V.x * E.x + V.y * E.y;
        }
        ((float4*)outr)[kb] = w;
    }
}

// Pair-swap 64x64 tiled transpose. Works in-place (In==Out) and out-of-place.
// Blocks with bj<bi exit; each active block handles tiles (bi,bj) and (bj,bi).
__global__ __launch_bounds__(256) void transpose_sw(const float* __restrict__ In,
                                                    float* __restrict__ Out) {
    int bi = blockIdx.y, bj = blockIdx.x;
    if (bj < bi) return;
    __shared__ float Ta[64][65];
    __shared__ float Tb[64][65];
    const int tid = threadIdx.x;
    const int c4 = (tid & 15) * 4;
    const int r0 = tid >> 4;                      // 0..15
    const bool diag = (bi == bj);
    #pragma unroll
    for (int k = 0; k < 4; ++k) {
        int r = r0 + 16 * k;
        float4 va = *(const float4*)&In[(size_t)(bi * 64 + r) * NF + bj * 64 + c4];
        Ta[r][c4] = va.x; Ta[r][c4 + 1] = va.y; Ta[r][c4 + 2] = va.z; Ta[r][c4 + 3] = va.w;
        if (!diag) {
            float4 vb = *(const float4*)&In[(size_t)(bj * 64 + r) * NF + bi * 64 + c4];
            Tb[r][c4] = vb.x; Tb[r][c4 + 1] = vb.y; Tb[r][c4 + 2] = vb.z; Tb[r][c4 + 3] = vb.w;
        }
    }
    __syncthreads();
    #pragma unroll
    for (int k = 0; k < 4; ++k) {
        int r = r0 + 16 * k;
        float4 wa;
        wa.x = Ta[c4][r]; wa.y = Ta[c4 + 1][r]; wa.z = Ta[c4 + 2][r]; wa.w = Ta[c4 + 3][r];
        *(float4*)&Out[(size_t)(bj * 64 + r) * NF + bi * 64 + c4] = wa;
        if (!diag) {
            float4 wb;
            wb.x = Tb[c4][r]; wb.y = Tb[c4 + 1][r]; wb.z = Tb[c4 + 2][r]; wb.w = Tb[c4 + 3][r];
            *(float4*)&Out[(size_t)(bi * 64 + r) * NF + bj * 64 + c4] = wb;
        }
    }
}

extern "C" void kernel_launch(void* const* d_in, const int* in_sizes, int n_in,
                              void* d_out, int out_size, void* d_ws, size_t ws_size,
                              hipStream_t stream) {
    const float* x = (const float*)d_in[0];
    float* out = (float*)d_out;

    float* tw = (float*)d_ws;           // 4672 float2 = 9344 floats
    float* ek = tw + 9344;              // 4096 float2 = 8192 floats
    float* B1 = ek + 8192;              // 4096*4096 floats (64 MB); offset 70144 B, 16B-aligned
    if (ws_size < (size_t)70144 + (size_t)NF * NF * sizeof(float)) return;

    setup_tables<<<35, 256, 0, stream>>>(tw, ek);
    dct_rows<<<NF, 256, 0, stream>>>(x, B1, tw, ek);          // rows of X -> B1 = Y
    transpose_sw<<<dim3(64, 64), 256, 0, stream>>>(B1, B1);   // B1 = Y^T (in-place)
    dct_rows<<<NF, 256, 0, stream>>>(B1, B1, tw, ek);         // rows of Y^T -> Z^T (in-place)
    transpose_sw<<<dim3(64, 64), 256, 0, stream>>>(B1, out);  // out = Z
}

// Round 3
// 219.852 us; speedup vs baseline: 2.0379x; 1.1855x over previous
//
#include <hip/hip_runtime.h>
#include <stdint.h>

// ---------------------------------------------------------------------------
// 2D DCT-II (unnormalized, 4096x4096 fp32) via the reference's own FFT path:
//   per row: v = makhoul_perm(x); V = FFT_4096(v); y[k] = Re(V[k]*expk[k])
// FFT_4096 = 4 radix-8 Stockham stages. v2: SINGLE 32 KB LDS buffer,
// butterflies in registers (read-all -> barrier -> write-all -> barrier),
// 512 thr/block (1 butterfly job each), stage 0 reads the Makhoul-permuted
// row straight from global (no LDS staging pass).
// Pipeline: setup -> dct_rows(X->B1) -> transpose(B1 inpl)
//                 -> dct_rows(B1 inpl) -> transpose(B1->out)
// LDS XOR swizzle phys(e)=e^((e>>3)&7) keeps stage reads conflict-free and
// caps write conflicts (~2 extra cyc/op measured in R2).
// ---------------------------------------------------------------------------

#define NF 4096

__device__ __forceinline__ int physi(int e) { return e ^ ((e >> 3) & 7); }

__device__ __forceinline__ float2 cadd(float2 a, float2 b) {
    float2 r; r.x = a.x + b.x; r.y = a.y + b.y; return r;
}
__device__ __forceinline__ float2 csub(float2 a, float2 b) {
    float2 r; r.x = a.x - b.x; r.y = a.y - b.y; return r;
}
__device__ __forceinline__ float2 cmulc(float2 a, float2 b) {
    float2 r; r.x = a.x * b.x - a.y * b.y; r.y = a.x * b.y + a.y * b.x; return r;
}
__device__ __forceinline__ float2 rotm(float2 a) {  // -i * a
    float2 r; r.x = a.y; r.y = -a.x; return r;
}

// tw: stages t=1..3, w[p][u] = exp(-2*pi*i*p*u/(8*Ls)), Ls=8,64,512.
//   float2 index: t=1 at 0 (64), t=2 at 64 (512), t=3 at 576 (4096). 4672 total.
// ek: expk[k] = (cos(pi*k/8192), sin(pi*k/8192)), 4096 entries.
__global__ __launch_bounds__(256) void setup_tables(float* __restrict__ tw,
                                                    float* __restrict__ ek) {
    int idx = blockIdx.x * 256 + threadIdx.x;
    if (idx < 4672) {
        int Ls, rel;
        if (idx < 64)       { Ls = 8;   rel = idx; }
        else if (idx < 576) { Ls = 64;  rel = idx - 64; }
        else                { Ls = 512; rel = idx - 576; }
        int p = rel >> 3, u = rel & 7;
        float phi = (float)(p * u) * (6.283185307179586f / (8.0f * (float)Ls));
        float s, c; __sincosf(phi, &s, &c);
        tw[2 * idx]     = c;
        tw[2 * idx + 1] = -s;
    } else if (idx < 8768) {
        int k = idx - 4672;
        float th = (float)k * (3.141592653589793f / 8192.0f);
        float s, c; __sincosf(th, &s, &c);
        ek[2 * k]     = c;
        ek[2 * k + 1] = s;
    }
}

// One workgroup (512 thr) = one row. In may equal Out (the whole row is
// consumed by stage 0 long before the epilogue stores).
__global__ __launch_bounds__(512) void dct_rows(const float* In,
                                                float* Out,
                                                const float* __restrict__ tw,
                                                const float* __restrict__ ek) {
    __shared__ float2 buf[NF];   // 32 KB, single buffer
    const int j = threadIdx.x;   // butterfly job 0..511
    const int row = blockIdx.x;
    const float* inr = In + (size_t)row * NF;
    float* outr = Out + (size_t)row * NF;

    float2 x[8];

    // ---- stage 0 (Ls=1): read Makhoul-permuted row directly from global
    #pragma unroll
    for (int k = 0; k < 8; ++k) {
        int n = j + 512 * k;
        int idx = (n < 2048) ? (2 * n) : (8191 - 2 * n);
        x[k].x = inr[idx];
        x[k].y = 0.0f;
    }
    {
        // radix-8 butterfly (no twiddle at t=0), outputs to wb=8j + r
        float2 t0 = cadd(x[0], x[4]), t1 = csub(x[0], x[4]);
        float2 t2 = cadd(x[2], x[6]), t3 = csub(x[2], x[6]);
        float2 E0 = cadd(t0, t2), E2 = csub(t0, t2);
        float2 r3 = rotm(t3);
        float2 E1 = cadd(t1, r3), E3 = csub(t1, r3);
        float2 s0 = cadd(x[1], x[5]), s1 = csub(x[1], x[5]);
        float2 s2 = cadd(x[3], x[7]), s3 = csub(x[3], x[7]);
        float2 O0 = cadd(s0, s2), O2 = csub(s0, s2);
        float2 r7 = rotm(s3);
        float2 O1 = cadd(s1, r7), O3 = csub(s1, r7);
        const float SQ = 0.7071067811865476f;
        float2 g1; g1.x = SQ * (O1.x + O1.y); g1.y = SQ * (O1.y - O1.x);
        float2 g2 = rotm(O2);
        float2 g3; g3.x = SQ * (O3.y - O3.x); g3.y = -SQ * (O3.x + O3.y);
        int wb = 8 * j;
        buf[physi(wb)]     = cadd(E0, O0);
        buf[physi(wb + 1)] = cadd(E1, g1);
        buf[physi(wb + 2)] = cadd(E2, g2);
        buf[physi(wb + 3)] = cadd(E3, g3);
        buf[physi(wb + 4)] = csub(E0, O0);
        buf[physi(wb + 5)] = csub(E1, g1);
        buf[physi(wb + 6)] = csub(E2, g2);
        buf[physi(wb + 7)] = csub(E3, g3);
    }
    __syncthreads();

    // ---- stages 1..3: read regs -> barrier -> write -> barrier
    #pragma unroll
    for (int t = 1; t < 4; ++t) {
        const int Ls = 1 << (3 * t);
        const int twoff = (t == 1) ? 0 : (t == 2) ? 64 : 576;
        const int p = j & (Ls - 1);
        const int q = j >> (3 * t);
        #pragma unroll
        for (int k = 0; k < 8; ++k)
            x[k] = buf[physi(j + 512 * k)];
        const float2* twp = (const float2*)tw + twoff + p * 8;
        #pragma unroll
        for (int k = 1; k < 8; ++k)
            x[k] = cmulc(x[k], twp[k]);
        float2 t0 = cadd(x[0], x[4]), t1 = csub(x[0], x[4]);
        float2 t2 = cadd(x[2], x[6]), t3 = csub(x[2], x[6]);
        float2 E0 = cadd(t0, t2), E2 = csub(t0, t2);
        float2 r3 = rotm(t3);
        float2 E1 = cadd(t1, r3), E3 = csub(t1, r3);
        float2 s0 = cadd(x[1], x[5]), s1 = csub(x[1], x[5]);
        float2 s2 = cadd(x[3], x[7]), s3 = csub(x[3], x[7]);
        float2 O0 = cadd(s0, s2), O2 = csub(s0, s2);
        float2 r7 = rotm(s3);
        float2 O1 = cadd(s1, r7), O3 = csub(s1, r7);
        const float SQ = 0.7071067811865476f;
        float2 g1; g1.x = SQ * (O1.x + O1.y); g1.y = SQ * (O1.y - O1.x);
        float2 g2 = rotm(O2);
        float2 g3; g3.x = SQ * (O3.y - O3.x); g3.y = -SQ * (O3.x + O3.y);
        __syncthreads();   // all reads of this stage done
        int wb = p + 8 * Ls * q;
        buf[physi(wb)]          = cadd(E0, O0);
        buf[physi(wb + Ls)]     = cadd(E1, g1);
        buf[physi(wb + 2 * Ls)] = cadd(E2, g2);
        buf[physi(wb + 3 * Ls)] = cadd(E3, g3);
        buf[physi(wb + 4 * Ls)] = csub(E0, O0);
        buf[physi(wb + 5 * Ls)] = csub(E1, g1);
        buf[physi(wb + 6 * Ls)] = csub(E2, g2);
        buf[physi(wb + 7 * Ls)] = csub(E3, g3);
        __syncthreads();   // all writes done
    }

    // ---- epilogue: y[k] = Vr*cos + Vi*sin, coalesced float4 stores
    #pragma unroll
    for (int i = 0; i < 2; ++i) {
        int kb = j + 512 * i;                 // float4 index 0..1023
        float4 w;
        float* wp = (float*)&w;
        #pragma unroll
        for (int c = 0; c < 4; ++c) {
            int k = 4 * kb + c;
            float2 V = buf[physi(k)];
            float2 E = ((const float2*)ek)[k];
            wp[c] = V.x * E.x + V.y * E.y;
        }
        ((float4*)outr)[kb] = w;
    }
}

// Pair-swap 64x64 tiled transpose. Works in-place (In==Out) and out-of-place.
__global__ __launch_bounds__(256) void transpose_sw(const float* __restrict__ In,
                                                    float* __restrict__ Out) {
    int bi = blockIdx.y, bj = blockIdx.x;
    if (bj < bi) return;
    __shared__ float Ta[64][65];
    __shared__ float Tb[64][65];
    const int tid = threadIdx.x;
    const int c4 = (tid & 15) * 4;
    const int r0 = tid >> 4;                      // 0..15
    const bool diag = (bi == bj);
    #pragma unroll
    for (int k = 0; k < 4; ++k) {
        int r = r0 + 16 * k;
        float4 va = *(const float4*)&In[(size_t)(bi * 64 + r) * NF + bj * 64 + c4];
        Ta[r][c4] = va.x; Ta[r][c4 + 1] = va.y; Ta[r][c4 + 2] = va.z; Ta[r][c4 + 3] = va.w;
        if (!diag) {
            float4 vb = *(const float4*)&In[(size_t)(bj * 64 + r) * NF + bi * 64 + c4];
            Tb[r][c4] = vb.x; Tb[r][c4 + 1] = vb.y; Tb[r][c4 + 2] = vb.z; Tb[r][c4 + 3] = vb.w;
        }
    }
    __syncthreads();
    #pragma unroll
    for (int k = 0; k < 4; ++k) {
        int r = r0 + 16 * k;
        float4 wa;
        wa.x = Ta[c4][r]; wa.y = Ta[c4 + 1][r]; wa.z = Ta[c4 + 2][r]; wa.w = Ta[c4 + 3][r];
        *(float4*)&Out[(size_t)(bj * 64 + r) * NF + bi * 64 + c4] = wa;
        if (!diag) {
            float4 wb;
            wb.x = Tb[c4][r]; wb.y = Tb[c4 + 1][r]; wb.z = Tb[c4 + 2][r]; wb.w = Tb[c4 + 3][r];
            *(float4*)&Out[(size_t)(bi * 64 + r) * NF + bj * 64 + c4] = wb;
        }
    }
}

extern "C" void kernel_launch(void* const* d_in, const int* in_sizes, int n_in,
                              void* d_out, int out_size, void* d_ws, size_t ws_size,
                              hipStream_t stream) {
    const float* x = (const float*)d_in[0];
    float* out = (float*)d_out;

    float* tw = (float*)d_ws;           // 4672 float2 = 9344 floats
    float* ek = tw + 9344;              // 4096 float2 = 8192 floats
    float* B1 = ek + 8192;              // 4096*4096 floats (64 MB)
    if (ws_size < (size_t)70144 + (size_t)NF * NF * sizeof(float)) return;

    setup_tables<<<35, 256, 0, stream>>>(tw, ek);
    dct_rows<<<NF, 512, 0, stream>>>(x, B1, tw, ek);          // rows of X -> B1 = Y
    transpose_sw<<<dim3(64, 64), 256, 0, stream>>>(B1, B1);   // B1 = Y^T (in-place)
    dct_rows<<<NF, 512, 0, stream>>>(B1, B1, tw, ek);         // rows of Y^T -> Z^T (in-place)
    transpose_sw<<<dim3(64, 64), 256, 0, stream>>>(B1, out);  // out = Z
}

// Round 4
// 204.568 us; speedup vs baseline: 2.1902x; 1.0747x over previous
//
#include <hip/hip_runtime.h>
#include <stdint.h>

// ---------------------------------------------------------------------------
// 2D DCT-II (unnormalized, 4096x4096 fp32), FFT path, v3:
//   TWO rows per workgroup packed z = row0 + i*row1 into ONE 4096-pt complex
//   FFT (4 radix-8 Stockham stages, single 32 KB LDS buffer, butterflies in
//   registers). Epilogue separates the pair via Hermitian symmetry and applies
//   the expk twiddle:
//     (a,b)=Z[k], (c,d)=Z[(N-k)&(N-1)], E=(cos,sin)(pi k/2N)
//     y0[k] = .5*((a+c)E.x + (b-d)E.y);  y1[k] = .5*((b+d)E.x - (a-c)E.y)
//   LDS swizzle phys(e)=e^((e>>4)&15): stage-0 scatter writes hit all 32
//   banks (was 16 with the 3-bit mask -> 2x write cost, 3.9M conflicts).
// Pipeline: setup -> dct_rows(X->B1) -> transpose(inpl) -> dct_rows(inpl)
//           -> transpose(B1->out)
// ---------------------------------------------------------------------------

#define NF 4096

__device__ __forceinline__ int physi(int e) { return e ^ ((e >> 4) & 15); }

__device__ __forceinline__ float2 cadd(float2 a, float2 b) {
    float2 r; r.x = a.x + b.x; r.y = a.y + b.y; return r;
}
__device__ __forceinline__ float2 csub(float2 a, float2 b) {
    float2 r; r.x = a.x - b.x; r.y = a.y - b.y; return r;
}
__device__ __forceinline__ float2 cmulc(float2 a, float2 b) {
    float2 r; r.x = a.x * b.x - a.y * b.y; r.y = a.x * b.y + a.y * b.x; return r;
}
__device__ __forceinline__ float2 rotm(float2 a) {  // -i * a
    float2 r; r.x = a.y; r.y = -a.x; return r;
}

// tw: stages t=1..3, w[p][u] = exp(-2*pi*i*p*u/(8*Ls)), Ls=8,64,512.
// ek: expk[k] = (cos(pi*k/8192), sin(pi*k/8192)), 4096 entries.
__global__ __launch_bounds__(256) void setup_tables(float* __restrict__ tw,
                                                    float* __restrict__ ek) {
    int idx = blockIdx.x * 256 + threadIdx.x;
    if (idx < 4672) {
        int Ls, rel;
        if (idx < 64)       { Ls = 8;   rel = idx; }
        else if (idx < 576) { Ls = 64;  rel = idx - 64; }
        else                { Ls = 512; rel = idx - 576; }
        int p = rel >> 3, u = rel & 7;
        float phi = (float)(p * u) * (6.283185307179586f / (8.0f * (float)Ls));
        float s, c; __sincosf(phi, &s, &c);
        tw[2 * idx]     = c;
        tw[2 * idx + 1] = -s;
    } else if (idx < 8768) {
        int k = idx - 4672;
        float th = (float)k * (3.141592653589793f / 8192.0f);
        float s, c; __sincosf(th, &s, &c);
        ek[2 * k]     = c;
        ek[2 * k + 1] = s;
    }
}

// One workgroup (512 thr) = TWO rows (2b, 2b+1). In may equal Out.
__global__ __launch_bounds__(512) void dct_rows(const float* In,
                                                float* Out,
                                                const float* __restrict__ tw,
                                                const float* __restrict__ ek) {
    __shared__ float2 buf[NF];   // 32 KB
    const int j = threadIdx.x;   // butterfly job 0..511
    const float* in0 = In + (size_t)(2 * blockIdx.x) * NF;
    const float* in1 = in0 + NF;
    float* out0 = Out + (size_t)(2 * blockIdx.x) * NF;
    float* out1 = out0 + NF;

    float2 x[8];

    // ---- stage 0 (Ls=1): Makhoul-permuted pair z = v0 + i*v1 from global
    #pragma unroll
    for (int k = 0; k < 8; ++k) {
        int n = j + 512 * k;
        int idx = (n < 2048) ? (2 * n) : (8191 - 2 * n);
        x[k].x = in0[idx];
        x[k].y = in1[idx];
    }
    {
        float2 t0 = cadd(x[0], x[4]), t1 = csub(x[0], x[4]);
        float2 t2 = cadd(x[2], x[6]), t3 = csub(x[2], x[6]);
        float2 E0 = cadd(t0, t2), E2 = csub(t0, t2);
        float2 r3 = rotm(t3);
        float2 E1 = cadd(t1, r3), E3 = csub(t1, r3);
        float2 s0 = cadd(x[1], x[5]), s1 = csub(x[1], x[5]);
        float2 s2 = cadd(x[3], x[7]), s3 = csub(x[3], x[7]);
        float2 O0 = cadd(s0, s2), O2 = csub(s0, s2);
        float2 r7 = rotm(s3);
        float2 O1 = cadd(s1, r7), O3 = csub(s1, r7);
        const float SQ = 0.7071067811865476f;
        float2 g1; g1.x = SQ * (O1.x + O1.y); g1.y = SQ * (O1.y - O1.x);
        float2 g2 = rotm(O2);
        float2 g3; g3.x = SQ * (O3.y - O3.x); g3.y = -SQ * (O3.x + O3.y);
        int wb = 8 * j;
        buf[physi(wb)]     = cadd(E0, O0);
        buf[physi(wb + 1)] = cadd(E1, g1);
        buf[physi(wb + 2)] = cadd(E2, g2);
        buf[physi(wb + 3)] = cadd(E3, g3);
        buf[physi(wb + 4)] = csub(E0, O0);
        buf[physi(wb + 5)] = csub(E1, g1);
        buf[physi(wb + 6)] = csub(E2, g2);
        buf[physi(wb + 7)] = csub(E3, g3);
    }
    __syncthreads();

    // ---- stages 1..3: read->barrier->write->barrier, single buffer
    #pragma unroll
    for (int t = 1; t < 4; ++t) {
        const int Ls = 1 << (3 * t);
        const int twoff = (t == 1) ? 0 : (t == 2) ? 64 : 576;
        const int p = j & (Ls - 1);
        const int q = j >> (3 * t);
        #pragma unroll
        for (int k = 0; k < 8; ++k)
            x[k] = buf[physi(j + 512 * k)];
        const float2* twp = (const float2*)tw + twoff + p * 8;
        #pragma unroll
        for (int k = 1; k < 8; ++k)
            x[k] = cmulc(x[k], twp[k]);
        float2 t0 = cadd(x[0], x[4]), t1 = csub(x[0], x[4]);
        float2 t2 = cadd(x[2], x[6]), t3 = csub(x[2], x[6]);
        float2 E0 = cadd(t0, t2), E2 = csub(t0, t2);
        float2 r3 = rotm(t3);
        float2 E1 = cadd(t1, r3), E3 = csub(t1, r3);
        float2 s0 = cadd(x[1], x[5]), s1 = csub(x[1], x[5]);
        float2 s2 = cadd(x[3], x[7]), s3 = csub(x[3], x[7]);
        float2 O0 = cadd(s0, s2), O2 = csub(s0, s2);
        float2 r7 = rotm(s3);
        float2 O1 = cadd(s1, r7), O3 = csub(s1, r7);
        const float SQ = 0.7071067811865476f;
        float2 g1; g1.x = SQ * (O1.x + O1.y); g1.y = SQ * (O1.y - O1.x);
        float2 g2 = rotm(O2);
        float2 g3; g3.x = SQ * (O3.y - O3.x); g3.y = -SQ * (O3.x + O3.y);
        __syncthreads();
        int wb = p + 8 * Ls * q;
        buf[physi(wb)]          = cadd(E0, O0);
        buf[physi(wb + Ls)]     = cadd(E1, g1);
        buf[physi(wb + 2 * Ls)] = cadd(E2, g2);
        buf[physi(wb + 3 * Ls)] = cadd(E3, g3);
        buf[physi(wb + 4 * Ls)] = csub(E0, O0);
        buf[physi(wb + 5 * Ls)] = csub(E1, g1);
        buf[physi(wb + 6 * Ls)] = csub(E2, g2);
        buf[physi(wb + 7 * Ls)] = csub(E3, g3);
        __syncthreads();
    }

    // ---- epilogue: Hermitian separation + expk twiddle; lane-consecutive k
    #pragma unroll
    for (int i = 0; i < 8; ++i) {
        int k = j + 512 * i;
        int m = (NF - k) & (NF - 1);
        float2 Zk = buf[physi(k)];
        float2 Zm = buf[physi(m)];
        float2 E = ((const float2*)ek)[k];
        out0[k] = 0.5f * ((Zk.x + Zm.x) * E.x + (Zk.y - Zm.y) * E.y);
        out1[k] = 0.5f * ((Zk.y + Zm.y) * E.x - (Zk.x - Zm.x) * E.y);
    }
}

// Pair-swap 64x64 tiled transpose. Works in-place (In==Out) and out-of-place.
__global__ __launch_bounds__(256) void transpose_sw(const float* __restrict__ In,
                                                    float* __restrict__ Out) {
    int bi = blockIdx.y, bj = blockIdx.x;
    if (bj < bi) return;
    __shared__ float Ta[64][65];
    __shared__ float Tb[64][65];
    const int tid = threadIdx.x;
    const int c4 = (tid & 15) * 4;
    const int r0 = tid >> 4;                      // 0..15
    const bool diag = (bi == bj);
    #pragma unroll
    for (int k = 0; k < 4; ++k) {
        int r = r0 + 16 * k;
        float4 va = *(const float4*)&In[(size_t)(bi * 64 + r) * NF + bj * 64 + c4];
        Ta[r][c4] = va.x; Ta[r][c4 + 1] = va.y; Ta[r][c4 + 2] = va.z; Ta[r][c4 + 3] = va.w;
        if (!diag) {
            float4 vb = *(const float4*)&In[(size_t)(bj * 64 + r) * NF + bi * 64 + c4];
            Tb[r][c4] = vb.x; Tb[r][c4 + 1] = vb.y; Tb[r][c4 + 2] = vb.z; Tb[r][c4 + 3] = vb.w;
        }
    }
    __syncthreads();
    #pragma unroll
    for (int k = 0; k < 4; ++k) {
        int r = r0 + 16 * k;
        float4 wa;
        wa.x = Ta[c4][r]; wa.y = Ta[c4 + 1][r]; wa.z = Ta[c4 + 2][r]; wa.w = Ta[c4 + 3][r];
        *(float4*)&Out[(size_t)(bj * 64 + r) * NF + bi * 64 + c4] = wa;
        if (!diag) {
            float4 wb;
            wb.x = Tb[c4][r]; wb.y = Tb[c4 + 1][r]; wb.z = Tb[c4 + 2][r]; wb.w = Tb[c4 + 3][r];
            *(float4*)&Out[(size_t)(bi * 64 + r) * NF + bj * 64 + c4] = wb;
        }
    }
}

extern "C" void kernel_launch(void* const* d_in, const int* in_sizes, int n_in,
                              void* d_out, int out_size, void* d_ws, size_t ws_size,
                              hipStream_t stream) {
    const float* x = (const float*)d_in[0];
    float* out = (float*)d_out;

    float* tw = (float*)d_ws;           // 4672 float2 = 9344 floats
    float* ek = tw + 9344;              // 4096 float2 = 8192 floats
    float* B1 = ek + 8192;              // 4096*4096 floats (64 MB)
    if (ws_size < (size_t)70144 + (size_t)NF * NF * sizeof(float)) return;

    setup_tables<<<35, 256, 0, stream>>>(tw, ek);
    dct_rows<<<NF / 2, 512, 0, stream>>>(x, B1, tw, ek);      // rows of X -> B1 = Y
    transpose_sw<<<dim3(64, 64), 256, 0, stream>>>(B1, B1);   // B1 = Y^T (in-place)
    dct_rows<<<NF / 2, 512, 0, stream>>>(B1, B1, tw, ek);     // rows of Y^T -> Z^T (in-place)
    transpose_sw<<<dim3(64, 64), 256, 0, stream>>>(B1, out);  // out = Z
}

// Round 5
// 200.355 us; speedup vs baseline: 2.2362x; 1.0210x over previous
//
#include <hip/hip_runtime.h>
#include <stdint.h>

// ---------------------------------------------------------------------------
// 2D DCT-II (unnormalized, 4096x4096 fp32), FFT path, v4:
//   Pair-packed rows (z = r0 + i*r1), 4096-pt complex FFT as 4 radix-8
//   Stockham stages in a single 32 KB LDS buffer, Hermitian-separation
//   epilogue with expk twiddle.
// v4 data flow (all transposes OUT-OF-PLACE, d_out used as scratch):
//   1. dct_rows<MK=1>  : X  -> B1   (Y;   Makhoul gather from global)
//   2. transpose_perm  : B1 -> out  (Y^T with next pass's Makhoul permute
//                                    folded into the output-column mapping)
//   3. dct_rows<MK=0>  : out -> B1  (Z^T; stage-0 reads fully coalesced)
//   4. transpose_plain : B1 -> out  (Z)
// dct v4 micro: stage 3 reads==writes per thread (one barrier dropped),
// stage-3 outputs kept in regs so epilogue only reads partner Zm from LDS.
// ---------------------------------------------------------------------------

#define NF 4096

__device__ __forceinline__ int physi(int e) { return e ^ ((e >> 4) & 15); }

__device__ __forceinline__ float2 cadd(float2 a, float2 b) {
    float2 r; r.x = a.x + b.x; r.y = a.y + b.y; return r;
}
__device__ __forceinline__ float2 csub(float2 a, float2 b) {
    float2 r; r.x = a.x - b.x; r.y = a.y - b.y; return r;
}
__device__ __forceinline__ float2 cmulc(float2 a, float2 b) {
    float2 r; r.x = a.x * b.x - a.y * b.y; r.y = a.x * b.y + a.y * b.x; return r;
}
__device__ __forceinline__ float2 rotm(float2 a) {  // -i * a
    float2 r; r.x = a.y; r.y = -a.x; return r;
}

// tw: stages t=1..3, w[p][u] = exp(-2*pi*i*p*u/(8*Ls)), Ls=8,64,512.
// ek: expk[k] = (cos(pi*k/8192), sin(pi*k/8192)), 4096 entries.
__global__ __launch_bounds__(256) void setup_tables(float* __restrict__ tw,
                                                    float* __restrict__ ek) {
    int idx = blockIdx.x * 256 + threadIdx.x;
    if (idx < 4672) {
        int Ls, rel;
        if (idx < 64)       { Ls = 8;   rel = idx; }
        else if (idx < 576) { Ls = 64;  rel = idx - 64; }
        else                { Ls = 512; rel = idx - 576; }
        int p = rel >> 3, u = rel & 7;
        float phi = (float)(p * u) * (6.283185307179586f / (8.0f * (float)Ls));
        float s, c; __sincosf(phi, &s, &c);
        tw[2 * idx]     = c;
        tw[2 * idx + 1] = -s;
    } else if (idx < 8768) {
        int k = idx - 4672;
        float th = (float)k * (3.141592653589793f / 8192.0f);
        float s, c; __sincosf(th, &s, &c);
        ek[2 * k]     = c;
        ek[2 * k + 1] = s;
    }
}

#define RADIX8(x, E0, E1, E2, E3, O0, g1, g2, g3)                              \
    float2 t0 = cadd(x[0], x[4]), t1 = csub(x[0], x[4]);                       \
    float2 t2 = cadd(x[2], x[6]), t3 = csub(x[2], x[6]);                       \
    float2 E0 = cadd(t0, t2), E2 = csub(t0, t2);                               \
    float2 r3 = rotm(t3);                                                      \
    float2 E1 = cadd(t1, r3), E3 = csub(t1, r3);                               \
    float2 s0 = cadd(x[1], x[5]), s1 = csub(x[1], x[5]);                       \
    float2 s2 = cadd(x[3], x[7]), s3 = csub(x[3], x[7]);                       \
    float2 O0 = cadd(s0, s2), O2 = csub(s0, s2);                               \
    float2 r7 = rotm(s3);                                                      \
    float2 O1 = cadd(s1, r7), O3 = csub(s1, r7);                               \
    const float SQ = 0.7071067811865476f;                                      \
    float2 g1; g1.x = SQ * (O1.x + O1.y); g1.y = SQ * (O1.y - O1.x);           \
    float2 g2 = rotm(O2);                                                      \
    float2 g3; g3.x = SQ * (O3.y - O3.x); g3.y = -SQ * (O3.x + O3.y);

// One workgroup (512 thr) = TWO rows (2b, 2b+1).
// MK=1: stage-0 applies the Makhoul gather (idx = 2n / 8191-2n).
// MK=0: input rows are pre-permuted (transpose_perm) -> linear coalesced reads.
template <int MK>
__global__ __launch_bounds__(512) void dct_rows(const float* __restrict__ In,
                                                float* __restrict__ Out,
                                                const float* __restrict__ tw,
                                                const float* __restrict__ ek) {
    __shared__ float2 buf[NF];   // 32 KB
    const int j = threadIdx.x;   // butterfly job 0..511
    const float* in0 = In + (size_t)(2 * blockIdx.x) * NF;
    const float* in1 = in0 + NF;
    float* out0 = Out + (size_t)(2 * blockIdx.x) * NF;
    float* out1 = out0 + NF;

    float2 x[8];

    // ---- stage 0 (Ls=1): read pair z = v0 + i*v1 from global
    #pragma unroll
    for (int k = 0; k < 8; ++k) {
        int n = j + 512 * k;
        int idx = MK ? ((n < 2048) ? (2 * n) : (8191 - 2 * n)) : n;
        x[k].x = in0[idx];
        x[k].y = in1[idx];
    }
    {
        RADIX8(x, E0, E1, E2, E3, O0, g1, g2, g3)
        int wb = 8 * j;
        buf[physi(wb)]     = cadd(E0, O0);
        buf[physi(wb + 1)] = cadd(E1, g1);
        buf[physi(wb + 2)] = cadd(E2, g2);
        buf[physi(wb + 3)] = cadd(E3, g3);
        buf[physi(wb + 4)] = csub(E0, O0);
        buf[physi(wb + 5)] = csub(E1, g1);
        buf[physi(wb + 6)] = csub(E2, g2);
        buf[physi(wb + 7)] = csub(E3, g3);
    }
    __syncthreads();

    // ---- stages 1..2: read->barrier->write->barrier
    #pragma unroll
    for (int t = 1; t < 3; ++t) {
        const int Ls = 1 << (3 * t);
        const int twoff = (t == 1) ? 0 : 64;
        const int p = j & (Ls - 1);
        const int q = j >> (3 * t);
        #pragma unroll
        for (int k = 0; k < 8; ++k)
            x[k] = buf[physi(j + 512 * k)];
        const float2* twp = (const float2*)tw + twoff + p * 8;
        #pragma unroll
        for (int k = 1; k < 8; ++k)
            x[k] = cmulc(x[k], twp[k]);
        RADIX8(x, E0, E1, E2, E3, O0, g1, g2, g3)
        __syncthreads();
        int wb = p + 8 * Ls * q;
        buf[physi(wb)]          = cadd(E0, O0);
        buf[physi(wb + Ls)]     = cadd(E1, g1);
        buf[physi(wb + 2 * Ls)] = cadd(E2, g2);
        buf[physi(wb + 3 * Ls)] = cadd(E3, g3);
        buf[physi(wb + 4 * Ls)] = csub(E0, O0);
        buf[physi(wb + 5 * Ls)] = csub(E1, g1);
        buf[physi(wb + 6 * Ls)] = csub(E2, g2);
        buf[physi(wb + 7 * Ls)] = csub(E3, g3);
        __syncthreads();
    }

    // ---- stage 3 (Ls=512, p=j, q=0): read-set == write-set per thread,
    // so no barrier between read and write; outputs kept in regs for epilogue.
    float2 o[8];
    {
        #pragma unroll
        for (int k = 0; k < 8; ++k)
            x[k] = buf[physi(j + 512 * k)];
        const float2* twp = (const float2*)tw + 576 + j * 8;
        #pragma unroll
        for (int k = 1; k < 8; ++k)
            x[k] = cmulc(x[k], twp[k]);
        RADIX8(x, E0, E1, E2, E3, O0, g1, g2, g3)
        o[0] = cadd(E0, O0); o[1] = cadd(E1, g1);
        o[2] = cadd(E2, g2); o[3] = cadd(E3, g3);
        o[4] = csub(E0, O0); o[5] = csub(E1, g1);
        o[6] = csub(E2, g2); o[7] = csub(E3, g3);
        #pragma unroll
        for (int r = 0; r < 8; ++r)
            buf[physi(j + 512 * r)] = o[r];   // own slots only
    }
    __syncthreads();

    // ---- epilogue: Zk = o[i] (regs); Zm from partner via LDS
    #pragma unroll
    for (int i = 0; i < 8; ++i) {
        int k = j + 512 * i;
        int m = (NF - k) & (NF - 1);
        float2 Zk = o[i];
        float2 Zm = buf[physi(m)];
        float2 E = ((const float2*)ek)[k];
        out0[k] = 0.5f * ((Zk.x + Zm.x) * E.x + (Zk.y - Zm.y) * E.y);
        out1[k] = 0.5f * ((Zk.y + Zm.y) * E.x - (Zk.x - Zm.x) * E.y);
    }
}

// Out-of-place transpose, one 64x64 tile per block: Out[c][r] = In[r][c].
// PERM=1 additionally maps the output-column index (= orig row R) through
// sigma^-1: even R -> R/2, odd R -> (8191-R)/2 (Makhoul pre-permute for the
// next dct pass). Per lane: orig rows c4..c4+3 -> one float2 at bi*32+c4/2
// (rows c4, c4+2) and one reversed float2 at 4094-bi*32-c4/2 (rows c4+3,c4+1).
template <int PERM>
__global__ __launch_bounds__(256) void transpose_t(const float* __restrict__ In,
                                                   float* __restrict__ Out) {
    int bi = blockIdx.y, bj = blockIdx.x;
    __shared__ float Ta[64][65];
    const int tid = threadIdx.x;
    const int c4 = (tid & 15) * 4;
    const int r0 = tid >> 4;                      // 0..15
    #pragma unroll
    for (int k = 0; k < 4; ++k) {
        int r = r0 + 16 * k;
        float4 va = *(const float4*)&In[(size_t)(bi * 64 + r) * NF + bj * 64 + c4];
        Ta[r][c4] = va.x; Ta[r][c4 + 1] = va.y; Ta[r][c4 + 2] = va.z; Ta[r][c4 + 3] = va.w;
    }
    __syncthreads();
    #pragma unroll
    for (int k = 0; k < 4; ++k) {
        int r = r0 + 16 * k;
        float* orow = &Out[(size_t)(bj * 64 + r) * NF];
        if (PERM) {
            float2 ev; ev.x = Ta[c4][r];     ev.y = Ta[c4 + 2][r];
            float2 od; od.x = Ta[c4 + 3][r]; od.y = Ta[c4 + 1][r];
            *(float2*)&orow[bi * 32 + (c4 >> 1)]        = ev;
            *(float2*)&orow[4094 - bi * 32 - (c4 >> 1)] = od;
        } else {
            float4 wa;
            wa.x = Ta[c4][r]; wa.y = Ta[c4 + 1][r];
            wa.z = Ta[c4 + 2][r]; wa.w = Ta[c4 + 3][r];
            *(float4*)&orow[bi * 64 + c4] = wa;
        }
    }
}

extern "C" void kernel_launch(void* const* d_in, const int* in_sizes, int n_in,
                              void* d_out, int out_size, void* d_ws, size_t ws_size,
                              hipStream_t stream) {
    const float* x = (const float*)d_in[0];
    float* out = (float*)d_out;

    float* tw = (float*)d_ws;           // 4672 float2 = 9344 floats
    float* ek = tw + 9344;              // 4096 float2 = 8192 floats
    float* B1 = ek + 8192;              // 4096*4096 floats (64 MB)
    if (ws_size < (size_t)70144 + (size_t)NF * NF * sizeof(float)) return;

    setup_tables<<<35, 256, 0, stream>>>(tw, ek);
    dct_rows<1><<<NF / 2, 512, 0, stream>>>(x, B1, tw, ek);     // B1 = Y
    transpose_t<1><<<dim3(64, 64), 256, 0, stream>>>(B1, out);  // out = mk(Y^T)
    dct_rows<0><<<NF / 2, 512, 0, stream>>>(out, B1, tw, ek);   // B1 = Z^T
    transpose_t<0><<<dim3(64, 64), 256, 0, stream>>>(B1, out);  // out = Z
}